// Round 7
// baseline (775.302 us; speedup 1.0000x reference)
//
#include <hip/hip_runtime.h>
#include <math.h>
#include <stdint.h>

#define NN 50000
#define NE 800000
#define HEADS 4
#define MPAD 50048  // NN rounded up to 128

typedef __attribute__((ext_vector_type(8))) short bf16x8;
typedef __attribute__((ext_vector_type(4))) float f32x4;

__device__ __forceinline__ uint32_t bf16rne(float x) {
  uint32_t b = __float_as_uint(x);
  return (b + 0x7FFFu + ((b >> 16) & 1u)) >> 16;
}
__device__ __forceinline__ float bflo(uint32_t v) {  // low ushort -> float
  return __uint_as_float(v << 16);
}
__device__ __forceinline__ float bfhi(uint32_t v) {  // high ushort -> float
  return __uint_as_float(v & 0xFFFF0000u);
}

// write one (hi|lo) pair of 16B granules into the swizzled 128B s-block
__device__ __forceinline__ void pair_write(const float v[8], char* rowp, int q, int x) {
  uint32_t hi[8], lo[8];
#pragma unroll
  for (int j = 0; j < 8; ++j) {
    hi[j] = bf16rne(v[j]);
    float back = __uint_as_float(hi[j] << 16);
    lo[j] = bf16rne(v[j] - back);
  }
  uint4 hp, lp;
  hp.x = hi[0] | (hi[1] << 16);
  hp.y = hi[2] | (hi[3] << 16);
  hp.z = hi[4] | (hi[5] << 16);
  hp.w = hi[6] | (hi[7] << 16);
  lp.x = lo[0] | (lo[1] << 16);
  lp.y = lo[2] | (lo[3] << 16);
  lp.z = lo[4] | (lo[5] << 16);
  lp.w = lo[6] | (lo[7] << 16);
  *(uint4*)(rowp + ((q ^ x) << 4)) = hp;
  *(uint4*)(rowp + (((4 | q) ^ x) << 4)) = lp;
}

// ---------------- CSR build (by dst) ----------------
__global__ void hist_kernel(const int* __restrict__ dst, int* __restrict__ counts, int n) {
  int i = blockIdx.x * blockDim.x + threadIdx.x;
  if (i < n) atomicAdd(&counts[dst[i]], 1);
}

// single-block exclusive scan; writes row_ptr AND cursor (scatter start offsets)
__global__ void scan_kernel(const int* __restrict__ counts, int* __restrict__ row_ptr,
                            int* __restrict__ cursor, int n) {
  __shared__ int wsum[16];
  const int lane = threadIdx.x & 63;
  const int w = threadIdx.x >> 6;
  int carry = 0;
  for (int start = 0; start < n; start += 1024) {
    int i = start + (int)threadIdx.x;
    int v = (i < n) ? counts[i] : 0;
    int x = v;
#pragma unroll
    for (int off = 1; off < 64; off <<= 1) {
      int t = __shfl_up(x, off);
      if (lane >= off) x += t;
    }
    if (lane == 63) wsum[w] = x;
    __syncthreads();
    if (w == 0 && lane < 16) {
      int s = wsum[lane];
#pragma unroll
      for (int off = 1; off < 16; off <<= 1) {
        int t = __shfl_up(s, off);
        if (lane >= off) s += t;
      }
      wsum[lane] = s;
    }
    __syncthreads();
    int woff = (w > 0) ? wsum[w - 1] : 0;
    int incl = x + woff;
    if (i < n) {
      int val = carry + incl - v;
      row_ptr[i] = val;
      cursor[i] = val;
    }
    carry += wsum[15];
    __syncthreads();
  }
  if (threadIdx.x == 0) row_ptr[n] = carry;
}

__global__ void scatter_kernel(const int* __restrict__ dst, const int* __restrict__ src,
                               int* __restrict__ cursor, int* __restrict__ srcs, int n) {
  int i = blockIdx.x * blockDim.x + threadIdx.x;
  if (i < n) {
    int pos = atomicAdd(&cursor[dst[i]], 1);
    srcs[pos] = src[i];
  }
}

// ---------------- single prepare kernel: A2-L1 + B2-L1 + B2-L2 pair-split ----------------
// Pair layout per 32-k block s: 8 granules of 16B; granule q^(row&7) = hi, (4|q)^(row&7) = lo.
// Swizzle baked into GLOBAL layout so global_load_lds staging stays linear (m173).
__global__ void prepare_kernel(const float* __restrict__ X, unsigned short* __restrict__ A2,
                               const float* __restrict__ W1, unsigned short* __restrict__ B2a,
                               const float* __restrict__ W2, unsigned short* __restrict__ B2b) {
  const int bid = blockIdx.x;
  const int wv = threadIdx.x >> 6;
  const int t = threadIdx.x & 63;
  const int s = t >> 2, q = t & 3;
  const int kb = s * 32 + q * 8;
  if (bid < 1024) {
    // A2-L1: init_emb rows, K=300, ksteps=10, row stride 1280B
    if (t >= 40) return;
    const int nw = 1024 * 4;
    for (int m = bid * 4 + wv; m < MPAD; m += nw) {
      float v[8];
#pragma unroll
      for (int j = 0; j < 8; ++j) {
        int k = kb + j;
        v[j] = (m < NN && k < 300) ? X[(size_t)m * 300 + k] : 0.f;
      }
      pair_write(v, (char*)A2 + (size_t)m * 1280 + s * 128, q, m & 7);
    }
  } else if (bid < 1152) {
    // B2a: W1[300][400] col n -> row n (512 rows, pad zero), ksteps=10
    if (t >= 40) return;
    const int n = (bid - 1024) * 4 + wv;
    float v[8];
#pragma unroll
    for (int j = 0; j < 8; ++j) {
      int k = kb + j;
      v[j] = (n < 400 && k < 300) ? W1[(size_t)k * 400 + n] : 0.f;
    }
    pair_write(v, (char*)B2a + (size_t)n * 1280 + s * 128, q, n & 7);
  } else {
    // B2b: W2[400][512] col n -> row n, head-padded K' = h*104 + d (d<100), ksteps=13
    if (t >= 52) return;
    const int n = (bid - 1152) * 4 + wv;
    float v[8];
#pragma unroll
    for (int j = 0; j < 8; ++j) {
      int kp = kb + j;
      int h = kp / 104;
      int d = kp - h * 104;
      v[j] = (d < 100) ? W2[(size_t)(h * 100 + d) * 512 + n] : 0.f;
    }
    pair_write(v, (char*)B2b + (size_t)n * 1664 + s * 128, q, n & 7);
  }
}

// ---------------- pair-split MFMA GEMM, bf16 output (head-padded layout) ----------------
// C = A@B via hi*hi + hi*lo + lo*hi. Both operands staged by 16B global_load_lds
// from pre-swizzled pair layout; ds_reads XOR-deswizzle (2-way conflicts = free).
__global__ __launch_bounds__(256, 2) void gemm_pairs(
    const unsigned short* __restrict__ A2, const unsigned short* __restrict__ B2,
    unsigned short* __restrict__ Ch, int M, int ksteps, int NstR, int RSc,
    int DHR, int DHP, int magic) {
  __shared__ unsigned short As[8192];  // 128 rows x 128B (hi|lo granules, swizzled)
  __shared__ unsigned short Bs[8192];
  const int tid = threadIdx.x;
  const int w = tid >> 6, lane = tid & 63;
  const int wr = w >> 1, wc = w & 1;
  const int ln = lane & 15, quad = lane >> 4;
  const int m0 = blockIdx.y * 128, n0 = blockIdx.x * 128;
  const long strideB = (long)ksteps * 128;  // bytes per row

  f32x4 acc[4][4];
#pragma unroll
  for (int mi = 0; mi < 4; ++mi)
#pragma unroll
    for (int ni = 0; ni < 4; ++ni) acc[mi][ni] = (f32x4){0.f, 0.f, 0.f, 0.f};

  const int xa = ln & 7;
  const int gA0 = (quad ^ xa) << 4, gA1 = ((4 | quad) ^ xa) << 4;

  for (int s = 0; s < ksteps; ++s) {
    const long sb = (long)s * 128;
#pragma unroll
    for (int j = 0; j < 4; ++j) {
      const int t16 = w * 4 + j;
      const int row = t16 * 8 + (lane >> 3);
      const int gran = lane & 7;
      const char* gpA = (const char*)A2 + (size_t)(m0 + row) * strideB + sb + gran * 16;
      const char* gpB = (const char*)B2 + (size_t)(n0 + row) * strideB + sb + gran * 16;
      __builtin_amdgcn_global_load_lds(
          (const __attribute__((address_space(1))) void*)gpA,
          (__attribute__((address_space(3))) void*)((char*)As + t16 * 1024), 16, 0, 0);
      __builtin_amdgcn_global_load_lds(
          (const __attribute__((address_space(1))) void*)gpB,
          (__attribute__((address_space(3))) void*)((char*)Bs + t16 * 1024), 16, 0, 0);
    }
    __syncthreads();
    bf16x8 ah[4], alo[4], bh[4], blo[4];
#pragma unroll
    for (int mi = 0; mi < 4; ++mi) {
      const int rA = wr * 64 + mi * 16 + ln;
      ah[mi] = *(const bf16x8*)((const char*)As + rA * 128 + gA0);
      alo[mi] = *(const bf16x8*)((const char*)As + rA * 128 + gA1);
    }
#pragma unroll
    for (int ni = 0; ni < 4; ++ni) {
      const int rB = wc * 64 + ni * 16 + ln;
      bh[ni] = *(const bf16x8*)((const char*)Bs + rB * 128 + gA0);
      blo[ni] = *(const bf16x8*)((const char*)Bs + rB * 128 + gA1);
    }
#pragma unroll
    for (int mi = 0; mi < 4; ++mi)
#pragma unroll
      for (int ni = 0; ni < 4; ++ni)
        acc[mi][ni] = __builtin_amdgcn_mfma_f32_16x16x32_bf16(ah[mi], bh[ni], acc[mi][ni], 0, 0, 0);
#pragma unroll
    for (int mi = 0; mi < 4; ++mi)
#pragma unroll
      for (int ni = 0; ni < 4; ++ni)
        acc[mi][ni] = __builtin_amdgcn_mfma_f32_16x16x32_bf16(ah[mi], blo[ni], acc[mi][ni], 0, 0, 0);
#pragma unroll
    for (int mi = 0; mi < 4; ++mi)
#pragma unroll
      for (int ni = 0; ni < 4; ++ni)
        acc[mi][ni] = __builtin_amdgcn_mfma_f32_16x16x32_bf16(alo[mi], bh[ni], acc[mi][ni], 0, 0, 0);
    __syncthreads();
  }
  // epilogue: fp32->bf16 rounding; head-padded column mapping
#pragma unroll
  for (int mi = 0; mi < 4; ++mi) {
#pragma unroll
    for (int r = 0; r < 4; ++r) {
      int gm = m0 + wr * 64 + mi * 16 + quad * 4 + r;
      if (gm < M) {
        unsigned short* crow = Ch + (size_t)gm * RSc;
#pragma unroll
        for (int ni = 0; ni < 4; ++ni) {
          int gn = n0 + wc * 64 + ni * 16 + ln;
          if (gn < NstR) {
            int h = (gn * magic) >> 12;
            int col = h * DHP + (gn - h * DHR);
            crow[col] = (unsigned short)bf16rne(acc[mi][ni][r]);
          }
        }
      }
    }
  }
}

// ---------------- el/er from bf16 proj (head-padded rows) ----------------
template <int DHR, int DHP>
__global__ void el_er_kernel(const unsigned short* __restrict__ projh,
                             const float* __restrict__ al, const float* __restrict__ ar,
                             float* __restrict__ el, float* __restrict__ er) {
  int t = blockIdx.x * blockDim.x + threadIdx.x;  // t = n*HEADS + h
  if (t >= NN * HEADS) return;
  int h = t & (HEADS - 1);
  int n = t >> 2;
  const unsigned short* pr = projh + (size_t)n * (HEADS * DHP) + (size_t)h * DHP;
  const float* alh = al + h * DHR;
  const float* arh = ar + h * DHR;
  float sl = 0.f, sr = 0.f;
#pragma unroll 4
  for (int d = 0; d < DHR; d += 4) {
    uint2 pv = *(const uint2*)&pr[d];
    float p0 = bflo(pv.x), p1 = bfhi(pv.x), p2 = bflo(pv.y), p3 = bfhi(pv.y);
    float4 av = *(const float4*)&alh[d];
    float4 rv = *(const float4*)&arh[d];
    sl += p0 * av.x + p1 * av.y + p2 * av.z + p3 * av.w;
    sr += p0 * rv.x + p1 * rv.y + p2 * rv.z + p3 * rv.w;
  }
  el[t] = sl;
  er[t] = sr;
}

// ---------------- fused edge softmax + aggregation, PERSISTENT waves ----------------
// Static node striding (wave wid handles nodes wid, wid+nw, ...): full residency for
// the kernel's duration, no work-stealing atomics (round-2 lesson), no block churn
// (round-1/5 lesson: 36% occupancy from 12.5K short-lived blocks). Per 16-edge chunk:
// p-phase computes exp/leaky for all (edge,head) pairs; next chunk's srcs+el are
// prefetched while the current chunk's 16 row-gathers are in flight.
// EMIT: emit layer-2 pair-split A2 rows directly (fuses layer-2 presplit; kills x1).
template <int DHP, int DHR, bool ACT, bool EMIT>
__global__ __launch_bounds__(256) void aggregate4(
    const unsigned short* __restrict__ projh, const float* __restrict__ el,
    const float* __restrict__ er, const float* __restrict__ bias,
    const int* __restrict__ row_ptr, const int* __restrict__ srcs,
    float* __restrict__ out, unsigned short* __restrict__ a2) {
  constexpr int LPH = DHP / 8;          // uint4 lanes per head (13 or 16)
  constexpr int RS = HEADS * DHP * 2;   // row stride bytes (832 or 1024)
  const int lane = threadIdx.x & 63;
  const int wid = blockIdx.x * 4 + (threadIdx.x >> 6);
  const int nw = gridDim.x * 4;
  // p-phase role: edge e16 = lane>>2, head hp = lane&3
  const int e16 = lane >> 2, hp = lane & 3;
  // gather-phase role: head, uint4-index u within head
  int head;
  if constexpr (LPH == 16) head = lane >> 4;
  else head = (lane * 5) >> 6;  // lane/13, exact for lane<64
  const int u = lane - head * LPH;
  const bool active = lane < 4 * LPH;
  // inactive lanes gather byte 0 of the row (same lines as lanes 0-3: no extra traffic)
  const int laneByte = active ? head * (DHP * 2) + u * 16 : 0;
  const char* pb = (const char*)projh;

  // bias (loop-invariant; predicated to avoid OOB on padded tail)
  float bv[8];
  const int d0 = u * 8;
#pragma unroll
  for (int j = 0; j < 8; ++j)
    bv[j] = (active && d0 + j < DHR) ? bias[head * DHR + d0 + j] : 0.f;

  for (int node = wid; node < NN; node += nw) {
    const int beg = row_ptr[node], end = row_ptr[node + 1];
    const float er_p = er[node * 4 + hp];

    float acc[8];
#pragma unroll
    for (int j = 0; j < 8; ++j) acc[j] = 0.f;
    float lsum = 0.f;

    int i = beg;
    int rem = end - beg;
    // prefetch chunk 0 p-inputs
    int sE = 0;
    float elv = 0.f;
    if (rem > 0 && e16 < rem) {
      sE = srcs[i + e16];
      elv = el[sE * 4 + hp];
    }
    while (rem > 0) {
      const int take = rem < 16 ? rem : 16;
      // ---- p-phase from prefetched inputs ----
      float ev = elv + er_p;
      ev = fmaxf(ev, 0.2f * ev);
      const float pv_ = (e16 < take) ? __expf(ev) : 0.f;
      const int off_ = sE * RS;
      // ---- prefetch next chunk's srcs + el ----
      const int i2 = i + take;
      const int rem2 = rem - take;
      int sEn = 0;
      float elvn = 0.f;
      if (rem2 > 0 && e16 < rem2) {
        sEn = srcs[i2 + e16];
        elvn = el[sEn * 4 + hp];
      }
      // ---- gather phase ----
      if (take == 16) {
#pragma unroll
        for (int e = 0; e < 16; ++e) {
          const int sl = e * 4 + head;
          const float pv = __shfl(pv_, sl);
          const int off = __shfl(off_, sl);
          uint4 q = *(const uint4*)(pb + (uint32_t)(off + laneByte));
          lsum += pv;
          acc[0] += pv * bflo(q.x);
          acc[1] += pv * bfhi(q.x);
          acc[2] += pv * bflo(q.y);
          acc[3] += pv * bfhi(q.y);
          acc[4] += pv * bflo(q.z);
          acc[5] += pv * bfhi(q.z);
          acc[6] += pv * bflo(q.w);
          acc[7] += pv * bfhi(q.w);
        }
      } else {
        for (int e = 0; e < take; ++e) {
          const int sl = e * 4 + head;
          const float pv = __shfl(pv_, sl);
          const int off = __shfl(off_, sl);
          uint4 q = *(const uint4*)(pb + (uint32_t)(off + laneByte));
          lsum += pv;
          acc[0] += pv * bflo(q.x);
          acc[1] += pv * bfhi(q.x);
          acc[2] += pv * bflo(q.y);
          acc[3] += pv * bfhi(q.y);
          acc[4] += pv * bflo(q.z);
          acc[5] += pv * bfhi(q.z);
          acc[6] += pv * bflo(q.w);
          acc[7] += pv * bfhi(q.w);
        }
      }
      sE = sEn;
      elv = elvn;
      i = i2;
      rem = rem2;
    }

    const float inv = 1.f / (lsum + 1e-9f);
    if (active) {
      float o[8];
#pragma unroll
      for (int j = 0; j < 8; ++j) {
        float v = acc[j] * inv + bv[j];
        if (ACT) v = (v > 0.f) ? v : 0.2f * v;
        o[j] = (d0 + j < DHR) ? v : 0.f;  // zero the head-pad (acc garbage there)
      }
      if constexpr (EMIT) {
        // emit pair-split A2 row (layer-2 GEMM A operand), stride 13*128 = 1664 B
        const int kp = head * DHP + u * 8;  // 8-aligned (DHP=104)
        const int s2 = kp >> 5, q2 = (kp >> 3) & 3;
        pair_write(o, (char*)a2 + (size_t)node * 1664 + s2 * 128, q2, node & 7);
      } else {
        float* orow = out + (size_t)node * (HEADS * DHR) + head * DHR + d0;
        *(float4*)orow = make_float4(o[0], o[1], o[2], o[3]);
        if (d0 + 7 < DHR) *(float4*)(orow + 4) = make_float4(o[4], o[5], o[6], o[7]);
      }
    }
  }
}

extern "C" void kernel_launch(void* const* d_in, const int* in_sizes, int n_in,
                              void* d_out, int out_size, void* d_ws, size_t ws_size,
                              hipStream_t stream) {
  const float* init_emb = (const float*)d_in[0];
  const float* W1 = (const float*)d_in[1];
  const float* al1 = (const float*)d_in[2];
  const float* ar1 = (const float*)d_in[3];
  const float* b1 = (const float*)d_in[4];
  const float* W2 = (const float*)d_in[5];
  const float* al2 = (const float*)d_in[6];
  const float* ar2 = (const float*)d_in[7];
  const float* b2 = (const float*)d_in[8];
  const int* src = (const int*)d_in[9];
  const int* dst = (const int*)d_in[10];
  float* out = (float*)d_out;

  // workspace carve-up; A2 pair-split buffer lives in d_out (dead until the final
  // aggregate, which only reads projh/el/er and then overwrites it).
  char* ws = (char*)d_ws;
  size_t off = 0;
  auto alloc = [&](size_t bytes) {
    void* p = ws + off;
    off += (bytes + 255) & ~((size_t)255);
    return p;
  };
  unsigned short* projh = (unsigned short*)alloc((size_t)NN * 512 * 2);  // bf16 proj (both layers)
  float* el = (float*)alloc((size_t)NN * HEADS * 4);
  float* er = (float*)alloc((size_t)NN * HEADS * 4);
  unsigned short* B2a = (unsigned short*)alloc((size_t)512 * 10 * 128);  // L1 weights
  unsigned short* B2b = (unsigned short*)alloc((size_t)512 * 13 * 128);  // L2 weights
  int* row_ptr = (int*)alloc((size_t)(NN + 1) * 4);
  int* counts = (int*)alloc((size_t)NN * 4);
  int* cursor = (int*)alloc((size_t)NN * 4);
  int* srcs = (int*)alloc((size_t)NE * 4);
  unsigned short* A2 = (unsigned short*)d_out;  // up to MPAD*13*128 = 83.3MB <= 102.4MB

  // --- prepare (A2-L1 + B2-L1 + B2-L2 pair-split, one launch) ---
  prepare_kernel<<<1280, 256, 0, stream>>>(init_emb, A2, W1, B2a, W2, B2b);

  // --- CSR build ---
  hipMemsetAsync(counts, 0, (size_t)NN * 4, stream);
  hist_kernel<<<(NE + 255) / 256, 256, 0, stream>>>(dst, counts, NE);
  scan_kernel<<<1, 1024, 0, stream>>>(counts, row_ptr, cursor, NN);
  scatter_kernel<<<(NE + 255) / 256, 256, 0, stream>>>(dst, src, cursor, srcs, NE);

  // --- layer 1: K=300 -> ksteps=10, N=400 (head-padded 4x104) ---
  gemm_pairs<<<dim3(4, MPAD / 128), 256, 0, stream>>>(A2, B2a, projh, NN, 10, 400, 416, 100, 104, 41);
  el_er_kernel<100, 104><<<(NN * HEADS + 255) / 256, 256, 0, stream>>>(projh, al1, ar1, el, er);
  // aggregate L1 emits layer-2's pair-split A2 directly (act1 fused, x1 eliminated)
  aggregate4<104, 100, true, true><<<2048, 256, 0, stream>>>(projh, el, er, b1, row_ptr,
                                                             srcs, nullptr, A2);

  // --- layer 2: head-padded K' = 4*104 = 416 -> ksteps=13, N=512 ---
  gemm_pairs<<<dim3(4, MPAD / 128), 256, 0, stream>>>(A2, B2b, projh, NN, 13, 512, 512, 128, 128, 32);
  el_er_kernel<128, 128><<<(NN * HEADS + 255) / 256, 256, 0, stream>>>(projh, al2, ar2, el, er);
  aggregate4<128, 128, false, false><<<2048, 256, 0, stream>>>(projh, el, er, b2, row_ptr,
                                                               srcs, out, nullptr);
}

// Round 9
// 745.073 us; speedup vs baseline: 1.0406x; 1.0406x over previous
//
#include <hip/hip_runtime.h>
#include <math.h>
#include <stdint.h>

#define NN 50000
#define NE 800000
#define HEADS 4
#define MPAD 50048  // NN rounded up to 128

typedef __attribute__((ext_vector_type(8))) short bf16x8;
typedef __attribute__((ext_vector_type(4))) float f32x4;
typedef __attribute__((ext_vector_type(4))) unsigned int u32x4;

__device__ __forceinline__ uint32_t bf16rne(float x) {
  uint32_t b = __float_as_uint(x);
  return (b + 0x7FFFu + ((b >> 16) & 1u)) >> 16;
}
__device__ __forceinline__ float bflo(uint32_t v) {  // low ushort -> float
  return __uint_as_float(v << 16);
}
__device__ __forceinline__ float bfhi(uint32_t v) {  // high ushort -> float
  return __uint_as_float(v & 0xFFFF0000u);
}

// split v[8] into (hi|lo) packed vectors
__device__ __forceinline__ void pair_pack(const float v[8], u32x4& hp, u32x4& lp) {
  uint32_t hi[8], lo[8];
#pragma unroll
  for (int j = 0; j < 8; ++j) {
    hi[j] = bf16rne(v[j]);
    float back = __uint_as_float(hi[j] << 16);
    lo[j] = bf16rne(v[j] - back);
  }
  hp.x = hi[0] | (hi[1] << 16);
  hp.y = hi[2] | (hi[3] << 16);
  hp.z = hi[4] | (hi[5] << 16);
  hp.w = hi[6] | (hi[7] << 16);
  lp.x = lo[0] | (lo[1] << 16);
  lp.y = lo[2] | (lo[3] << 16);
  lp.z = lo[4] | (lo[5] << 16);
  lp.w = lo[6] | (lo[7] << 16);
}

// write one (hi|lo) pair of 16B granules into the swizzled 128B s-block
__device__ __forceinline__ void pair_write(const float v[8], char* rowp, int q, int x) {
  u32x4 hp, lp;
  pair_pack(v, hp, lp);
  *(u32x4*)(rowp + ((q ^ x) << 4)) = hp;
  *(u32x4*)(rowp + (((4 | q) ^ x) << 4)) = lp;
}

// NT variant: bypass cache allocation (avoid polluting L2/L3 gather residency)
__device__ __forceinline__ void pair_write_nt(const float v[8], char* rowp, int q, int x) {
  u32x4 hp, lp;
  pair_pack(v, hp, lp);
  __builtin_nontemporal_store(hp, (u32x4*)(rowp + ((q ^ x) << 4)));
  __builtin_nontemporal_store(lp, (u32x4*)(rowp + (((4 | q) ^ x) << 4)));
}

// ---------------- CSR build (by dst) ----------------
// single-block exclusive scan; writes row_ptr AND cursor (scatter start offsets)
__global__ void scan_kernel(const int* __restrict__ counts, int* __restrict__ row_ptr,
                            int* __restrict__ cursor, int n) {
  __shared__ int wsum[16];
  const int lane = threadIdx.x & 63;
  const int w = threadIdx.x >> 6;
  int carry = 0;
  for (int start = 0; start < n; start += 1024) {
    int i = start + (int)threadIdx.x;
    int v = (i < n) ? counts[i] : 0;
    int x = v;
#pragma unroll
    for (int off = 1; off < 64; off <<= 1) {
      int t = __shfl_up(x, off);
      if (lane >= off) x += t;
    }
    if (lane == 63) wsum[w] = x;
    __syncthreads();
    if (w == 0 && lane < 16) {
      int s = wsum[lane];
#pragma unroll
      for (int off = 1; off < 16; off <<= 1) {
        int t = __shfl_up(s, off);
        if (lane >= off) s += t;
      }
      wsum[lane] = s;
    }
    __syncthreads();
    int woff = (w > 0) ? wsum[w - 1] : 0;
    int incl = x + woff;
    if (i < n) {
      int val = carry + incl - v;
      row_ptr[i] = val;
      cursor[i] = val;
    }
    carry += wsum[15];
    __syncthreads();
  }
  if (threadIdx.x == 0) row_ptr[n] = carry;
}

__global__ void scatter_kernel(const int* __restrict__ dst, const int* __restrict__ src,
                               int* __restrict__ cursor, int* __restrict__ srcs, int n) {
  int i = blockIdx.x * blockDim.x + threadIdx.x;
  if (i < n) {
    int pos = atomicAdd(&cursor[dst[i]], 1);
    srcs[pos] = src[i];
  }
}

// ---------------- prepare kernel: A2-L1 + B2-L1 + B2-L2 pair-split + dst histogram ----------
// Pair layout per 32-k block s: 8 granules of 16B; granule q^(row&7) = hi, (4|q)^(row&7) = lo.
// Swizzle baked into GLOBAL layout so global_load_lds staging stays linear (m173).
// bid >= 1280: fused dst-histogram blocks (independent work, saves a launch).
__global__ void prepare_kernel(const float* __restrict__ X, unsigned short* __restrict__ A2,
                               const float* __restrict__ W1, unsigned short* __restrict__ B2a,
                               const float* __restrict__ W2, unsigned short* __restrict__ B2b,
                               const int* __restrict__ dst, int* __restrict__ counts) {
  const int bid = blockIdx.x;
  if (bid >= 1280) {
    int e = (bid - 1280) * 256 + (int)threadIdx.x;
    if (e < NE) atomicAdd(&counts[dst[e]], 1);
    return;
  }
  const int wv = threadIdx.x >> 6;
  const int t = threadIdx.x & 63;
  const int s = t >> 2, q = t & 3;
  const int kb = s * 32 + q * 8;
  if (bid < 1024) {
    // A2-L1: init_emb rows, K=300, ksteps=10, row stride 1280B
    if (t >= 40) return;
    const int nw = 1024 * 4;
    for (int m = bid * 4 + wv; m < MPAD; m += nw) {
      float v[8];
#pragma unroll
      for (int j = 0; j < 8; ++j) {
        int k = kb + j;
        v[j] = (m < NN && k < 300) ? X[(size_t)m * 300 + k] : 0.f;
      }
      pair_write(v, (char*)A2 + (size_t)m * 1280 + s * 128, q, m & 7);
    }
  } else if (bid < 1152) {
    // B2a: W1[300][400] col n -> row n (512 rows, pad zero), ksteps=10
    if (t >= 40) return;
    const int n = (bid - 1024) * 4 + wv;
    float v[8];
#pragma unroll
    for (int j = 0; j < 8; ++j) {
      int k = kb + j;
      v[j] = (n < 400 && k < 300) ? W1[(size_t)k * 400 + n] : 0.f;
    }
    pair_write(v, (char*)B2a + (size_t)n * 1280 + s * 128, q, n & 7);
  } else {
    // B2b: W2[400][512] col n -> row n, head-padded K' = h*104 + d (d<100), ksteps=13
    if (t >= 52) return;
    const int n = (bid - 1152) * 4 + wv;
    float v[8];
#pragma unroll
    for (int j = 0; j < 8; ++j) {
      int kp = kb + j;
      int h = kp / 104;
      int d = kp - h * 104;
      v[j] = (d < 100) ? W2[(size_t)(h * 100 + d) * 512 + n] : 0.f;
    }
    pair_write(v, (char*)B2b + (size_t)n * 1664 + s * 128, q, n & 7);
  }
}

// ---------------- pair-split MFMA GEMM, bf16 output (head-padded layout) ----------------
// C = A@B via hi*hi + hi*lo + lo*hi. Both operands staged by 16B global_load_lds
// from pre-swizzled pair layout; ds_reads XOR-deswizzle (2-way conflicts = free).
// 3 blocks/CU for cross-block phase overlap at tiny K.
__global__ __launch_bounds__(256, 3) void gemm_pairs(
    const unsigned short* __restrict__ A2, const unsigned short* __restrict__ B2,
    unsigned short* __restrict__ Ch, int M, int ksteps, int NstR, int RSc,
    int DHR, int DHP, int magic) {
  __shared__ unsigned short As[8192];  // 128 rows x 128B (hi|lo granules, swizzled)
  __shared__ unsigned short Bs[8192];
  const int tid = threadIdx.x;
  const int w = tid >> 6, lane = tid & 63;
  const int wr = w >> 1, wc = w & 1;
  const int ln = lane & 15, quad = lane >> 4;
  const int m0 = blockIdx.y * 128, n0 = blockIdx.x * 128;
  const long strideB = (long)ksteps * 128;  // bytes per row

  f32x4 acc[4][4];
#pragma unroll
  for (int mi = 0; mi < 4; ++mi)
#pragma unroll
    for (int ni = 0; ni < 4; ++ni) acc[mi][ni] = (f32x4){0.f, 0.f, 0.f, 0.f};

  const int xa = ln & 7;
  const int gA0 = (quad ^ xa) << 4, gA1 = ((4 | quad) ^ xa) << 4;

  for (int s = 0; s < ksteps; ++s) {
    const long sb = (long)s * 128;
#pragma unroll
    for (int j = 0; j < 4; ++j) {
      const int t16 = w * 4 + j;
      const int row = t16 * 8 + (lane >> 3);
      const int gran = lane & 7;
      const char* gpA = (const char*)A2 + (size_t)(m0 + row) * strideB + sb + gran * 16;
      const char* gpB = (const char*)B2 + (size_t)(n0 + row) * strideB + sb + gran * 16;
      __builtin_amdgcn_global_load_lds(
          (const __attribute__((address_space(1))) void*)gpA,
          (__attribute__((address_space(3))) void*)((char*)As + t16 * 1024), 16, 0, 0);
      __builtin_amdgcn_global_load_lds(
          (const __attribute__((address_space(1))) void*)gpB,
          (__attribute__((address_space(3))) void*)((char*)Bs + t16 * 1024), 16, 0, 0);
    }
    __syncthreads();
    bf16x8 ah[4], alo[4], bh[4], blo[4];
#pragma unroll
    for (int mi = 0; mi < 4; ++mi) {
      const int rA = wr * 64 + mi * 16 + ln;
      ah[mi] = *(const bf16x8*)((const char*)As + rA * 128 + gA0);
      alo[mi] = *(const bf16x8*)((const char*)As + rA * 128 + gA1);
    }
#pragma unroll
    for (int ni = 0; ni < 4; ++ni) {
      const int rB = wc * 64 + ni * 16 + ln;
      bh[ni] = *(const bf16x8*)((const char*)Bs + rB * 128 + gA0);
      blo[ni] = *(const bf16x8*)((const char*)Bs + rB * 128 + gA1);
    }
#pragma unroll
    for (int mi = 0; mi < 4; ++mi)
#pragma unroll
      for (int ni = 0; ni < 4; ++ni)
        acc[mi][ni] = __builtin_amdgcn_mfma_f32_16x16x32_bf16(ah[mi], bh[ni], acc[mi][ni], 0, 0, 0);
#pragma unroll
    for (int mi = 0; mi < 4; ++mi)
#pragma unroll
      for (int ni = 0; ni < 4; ++ni)
        acc[mi][ni] = __builtin_amdgcn_mfma_f32_16x16x32_bf16(ah[mi], blo[ni], acc[mi][ni], 0, 0, 0);
#pragma unroll
    for (int mi = 0; mi < 4; ++mi)
#pragma unroll
      for (int ni = 0; ni < 4; ++ni)
        acc[mi][ni] = __builtin_amdgcn_mfma_f32_16x16x32_bf16(alo[mi], bh[ni], acc[mi][ni], 0, 0, 0);
    __syncthreads();
  }
  // epilogue: fp32->bf16 rounding; head-padded column mapping
#pragma unroll
  for (int mi = 0; mi < 4; ++mi) {
#pragma unroll
    for (int r = 0; r < 4; ++r) {
      int gm = m0 + wr * 64 + mi * 16 + quad * 4 + r;
      if (gm < M) {
        unsigned short* crow = Ch + (size_t)gm * RSc;
#pragma unroll
        for (int ni = 0; ni < 4; ++ni) {
          int gn = n0 + wc * 64 + ni * 16 + ln;
          if (gn < NstR) {
            int h = (gn * magic) >> 12;
            int col = h * DHP + (gn - h * DHR);
            crow[col] = (unsigned short)bf16rne(acc[mi][ni][r]);
          }
        }
      }
    }
  }
}

// ---------------- el/er from bf16 proj (head-padded rows) ----------------
template <int DHR, int DHP>
__global__ void el_er_kernel(const unsigned short* __restrict__ projh,
                             const float* __restrict__ al, const float* __restrict__ ar,
                             float* __restrict__ el, float* __restrict__ er) {
  int t = blockIdx.x * blockDim.x + threadIdx.x;  // t = n*HEADS + h
  if (t >= NN * HEADS) return;
  int h = t & (HEADS - 1);
  int n = t >> 2;
  const unsigned short* pr = projh + (size_t)n * (HEADS * DHP) + (size_t)h * DHP;
  const float* alh = al + h * DHR;
  const float* arh = ar + h * DHR;
  float sl = 0.f, sr = 0.f;
#pragma unroll 4
  for (int d = 0; d < DHR; d += 4) {
    uint2 pv = *(const uint2*)&pr[d];
    float p0 = bflo(pv.x), p1 = bfhi(pv.x), p2 = bflo(pv.y), p3 = bfhi(pv.y);
    float4 av = *(const float4*)&alh[d];
    float4 rv = *(const float4*)&arh[d];
    sl += p0 * av.x + p1 * av.y + p2 * av.z + p3 * av.w;
    sr += p0 * rv.x + p1 * rv.y + p2 * rv.z + p3 * rv.w;
  }
  el[t] = sl;
  er[t] = sr;
}

// ---------------- fused edge softmax + aggregation, persistent waves ----------------
// Static node striding. All output stores are NON-TEMPORAL: the store stream
// (83-102 MB/dispatch) otherwise allocates in L2/L3 and evicts the gather-resident
// projh lines (probe: FETCH_SIZE 409 MB vs 51 MB resident table = 50% hit only).
// EMIT: emit layer-2 pair-split A2 rows directly (fuses layer-2 presplit; kills x1).
template <int DHP, int DHR, bool ACT, bool EMIT>
__global__ __launch_bounds__(256) void aggregate4(
    const unsigned short* __restrict__ projh, const float* __restrict__ el,
    const float* __restrict__ er, const float* __restrict__ bias,
    const int* __restrict__ row_ptr, const int* __restrict__ srcs,
    float* __restrict__ out, unsigned short* __restrict__ a2) {
  constexpr int LPH = DHP / 8;          // uint4 lanes per head (13 or 16)
  constexpr int RS = HEADS * DHP * 2;   // row stride bytes (832 or 1024)
  const int lane = threadIdx.x & 63;
  const int wid = blockIdx.x * 4 + (threadIdx.x >> 6);
  const int nw = gridDim.x * 4;
  // p-phase role: edge e16 = lane>>2, head hp = lane&3
  const int e16 = lane >> 2, hp = lane & 3;
  // gather-phase role: head, uint4-index u within head
  int head;
  if constexpr (LPH == 16) head = lane >> 4;
  else head = (lane * 5) >> 6;  // lane/13, exact for lane<64
  const int u = lane - head * LPH;
  const bool active = lane < 4 * LPH;
  // inactive lanes gather byte 0 of the row (same lines as lanes 0-3: no extra traffic)
  const int laneByte = active ? head * (DHP * 2) + u * 16 : 0;
  const char* pb = (const char*)projh;

  // bias (loop-invariant; predicated to avoid OOB on padded tail)
  float bv[8];
  const int d0 = u * 8;
#pragma unroll
  for (int j = 0; j < 8; ++j)
    bv[j] = (active && d0 + j < DHR) ? bias[head * DHR + d0 + j] : 0.f;

  for (int node = wid; node < NN; node += nw) {
    const int beg = row_ptr[node], end = row_ptr[node + 1];
    const float er_p = er[node * 4 + hp];

    float acc[8];
#pragma unroll
    for (int j = 0; j < 8; ++j) acc[j] = 0.f;
    float lsum = 0.f;

    int i = beg;
    int rem = end - beg;
    // prefetch chunk 0 p-inputs
    int sE = 0;
    float elv = 0.f;
    if (rem > 0 && e16 < rem) {
      sE = srcs[i + e16];
      elv = el[sE * 4 + hp];
    }
    while (rem > 0) {
      const int take = rem < 16 ? rem : 16;
      // ---- p-phase from prefetched inputs ----
      float ev = elv + er_p;
      ev = fmaxf(ev, 0.2f * ev);
      const float pv_ = (e16 < take) ? __expf(ev) : 0.f;
      const int off_ = sE * RS;
      // ---- prefetch next chunk's srcs + el ----
      const int i2 = i + take;
      const int rem2 = rem - take;
      int sEn = 0;
      float elvn = 0.f;
      if (rem2 > 0 && e16 < rem2) {
        sEn = srcs[i2 + e16];
        elvn = el[sEn * 4 + hp];
      }
      // ---- gather phase ----
      if (take == 16) {
#pragma unroll
        for (int e = 0; e < 16; ++e) {
          const int sl = e * 4 + head;
          const float pv = __shfl(pv_, sl);
          const int off = __shfl(off_, sl);
          u32x4 q = *(const u32x4*)(pb + (uint32_t)(off + laneByte));
          lsum += pv;
          acc[0] += pv * bflo(q.x);
          acc[1] += pv * bfhi(q.x);
          acc[2] += pv * bflo(q.y);
          acc[3] += pv * bfhi(q.y);
          acc[4] += pv * bflo(q.z);
          acc[5] += pv * bfhi(q.z);
          acc[6] += pv * bflo(q.w);
          acc[7] += pv * bfhi(q.w);
        }
      } else {
        for (int e = 0; e < take; ++e) {
          const int sl = e * 4 + head;
          const float pv = __shfl(pv_, sl);
          const int off = __shfl(off_, sl);
          u32x4 q = *(const u32x4*)(pb + (uint32_t)(off + laneByte));
          lsum += pv;
          acc[0] += pv * bflo(q.x);
          acc[1] += pv * bfhi(q.x);
          acc[2] += pv * bflo(q.y);
          acc[3] += pv * bfhi(q.y);
          acc[4] += pv * bflo(q.z);
          acc[5] += pv * bfhi(q.z);
          acc[6] += pv * bflo(q.w);
          acc[7] += pv * bfhi(q.w);
        }
      }
      sE = sEn;
      elv = elvn;
      i = i2;
      rem = rem2;
    }

    const float inv = 1.f / (lsum + 1e-9f);
    if (active) {
      float o[8];
#pragma unroll
      for (int j = 0; j < 8; ++j) {
        float v = acc[j] * inv + bv[j];
        if (ACT) v = (v > 0.f) ? v : 0.2f * v;
        o[j] = (d0 + j < DHR) ? v : 0.f;  // zero the head-pad (acc garbage there)
      }
      if constexpr (EMIT) {
        // emit pair-split A2 row (layer-2 GEMM A operand), stride 13*128 = 1664 B
        const int kp = head * DHP + u * 8;  // 8-aligned (DHP=104)
        const int s2 = kp >> 5, q2 = (kp >> 3) & 3;
        pair_write_nt(o, (char*)a2 + (size_t)node * 1664 + s2 * 128, q2, node & 7);
      } else {
        float* orow = out + (size_t)node * (HEADS * DHR) + head * DHR + d0;
        f32x4 o0 = {o[0], o[1], o[2], o[3]};
        __builtin_nontemporal_store(o0, (f32x4*)orow);
        if (d0 + 7 < DHR) {
          f32x4 o1 = {o[4], o[5], o[6], o[7]};
          __builtin_nontemporal_store(o1, (f32x4*)(orow + 4));
        }
      }
    }
  }
}

extern "C" void kernel_launch(void* const* d_in, const int* in_sizes, int n_in,
                              void* d_out, int out_size, void* d_ws, size_t ws_size,
                              hipStream_t stream) {
  const float* init_emb = (const float*)d_in[0];
  const float* W1 = (const float*)d_in[1];
  const float* al1 = (const float*)d_in[2];
  const float* ar1 = (const float*)d_in[3];
  const float* b1 = (const float*)d_in[4];
  const float* W2 = (const float*)d_in[5];
  const float* al2 = (const float*)d_in[6];
  const float* ar2 = (const float*)d_in[7];
  const float* b2 = (const float*)d_in[8];
  const int* src = (const int*)d_in[9];
  const int* dst = (const int*)d_in[10];
  float* out = (float*)d_out;

  // workspace carve-up; A2 pair-split buffer lives in d_out (dead until the final
  // aggregate, which only reads projh/el/er and then overwrites it).
  char* ws = (char*)d_ws;
  size_t off = 0;
  auto alloc = [&](size_t bytes) {
    void* p = ws + off;
    off += (bytes + 255) & ~((size_t)255);
    return p;
  };
  unsigned short* projh = (unsigned short*)alloc((size_t)NN * 512 * 2);  // bf16 proj (both layers)
  float* el = (float*)alloc((size_t)NN * HEADS * 4);
  float* er = (float*)alloc((size_t)NN * HEADS * 4);
  unsigned short* B2a = (unsigned short*)alloc((size_t)512 * 10 * 128);  // L1 weights
  unsigned short* B2b = (unsigned short*)alloc((size_t)512 * 13 * 128);  // L2 weights
  int* row_ptr = (int*)alloc((size_t)(NN + 1) * 4);
  int* counts = (int*)alloc((size_t)NN * 4);
  int* cursor = (int*)alloc((size_t)NN * 4);
  int* srcs = (int*)alloc((size_t)NE * 4);
  unsigned short* A2 = (unsigned short*)d_out;  // up to MPAD*13*128 = 83.3MB <= 102.4MB

  // --- prepare (A2-L1 + B2-L1 + B2-L2 pair-split + dst histogram, one launch) ---
  hipMemsetAsync(counts, 0, (size_t)NN * 4, stream);
  prepare_kernel<<<1280 + (NE + 255) / 256, 256, 0, stream>>>(init_emb, A2, W1, B2a, W2, B2b,
                                                              dst, counts);
  scan_kernel<<<1, 1024, 0, stream>>>(counts, row_ptr, cursor, NN);
  scatter_kernel<<<(NE + 255) / 256, 256, 0, stream>>>(dst, src, cursor, srcs, NE);

  // --- layer 1: K=300 -> ksteps=10, N=400 (head-padded 4x104) ---
  gemm_pairs<<<dim3(4, MPAD / 128), 256, 0, stream>>>(A2, B2a, projh, NN, 10, 400, 416, 100, 104, 41);
  el_er_kernel<100, 104><<<(NN * HEADS + 255) / 256, 256, 0, stream>>>(projh, al1, ar1, el, er);
  // aggregate L1 emits layer-2's pair-split A2 directly (act1 fused, x1 eliminated)
  aggregate4<104, 100, true, true><<<2048, 256, 0, stream>>>(projh, el, er, b1, row_ptr,
                                                             srcs, nullptr, A2);

  // --- layer 2: head-padded K' = 4*104 = 416 -> ksteps=13, N=512 ---
  gemm_pairs<<<dim3(4, MPAD / 128), 256, 0, stream>>>(A2, B2b, projh, NN, 13, 512, 512, 128, 128, 32);
  el_er_kernel<128, 128><<<(NN * HEADS + 255) / 256, 256, 0, stream>>>(projh, al2, ar2, el, er);
  aggregate4<128, 128, false, false><<<2048, 256, 0, stream>>>(projh, el, er, b2, row_ptr,
                                                               srcs, out, nullptr);
}